// Round 1
// baseline (965.842 us; speedup 1.0000x reference)
//
#include <hip/hip_runtime.h>

typedef unsigned short u16;
typedef unsigned int   u32;
typedef __attribute__((ext_vector_type(4))) float floatx4;
typedef __attribute__((ext_vector_type(8))) short shortx8;
typedef __attribute__((ext_vector_type(8))) u16   ushortx8;

#define B_   2
#define S_   2048
#define DIM_ 4096
#define NH_  32
#define NKV_ 8
#define HD_  128
#define MTOT (B_*S_)            // 4096 rows
#define NQKV (NH_*HD_ + 2*NKV_*HD_)  // 6144
// Q pre-scale: 1/sqrt(128) * log2(e)  -> scores in log2 domain, softmax uses exp2
#define QSCALE 0.12753785735803168f
#define KSCALE 1.0f

typedef __attribute__((address_space(3))) u32 lds_u32;
typedef const __attribute__((address_space(1))) u32 gbl_u32;

__device__ inline u16 f2bf(float f) {                 // native RNE cvt
  __bf16 h = (__bf16)f;
  return __builtin_bit_cast(u16, h);
}
__device__ inline float bf2f(u16 u) {
  u32 x = ((u32)u) << 16;
  return __builtin_bit_cast(float, x);
}
__device__ inline shortx8 ldfrag(const u16* p) {
  return __builtin_bit_cast(shortx8, *(const uint4*)p);
}

// ---------------- fp32 -> bf16 cast (x) ----------------
__global__ __launch_bounds__(256) void cvt_f32_bf16(const float* __restrict__ src,
                                                    u16* __restrict__ dst) {
  int i = blockIdx.x * 256 + threadIdx.x;          // 8 elems / thread
  const float4* s4 = (const float4*)src;
  float4 a = s4[2*i], c = s4[2*i+1];
  ushortx8 o;
  o[0]=f2bf(a.x); o[1]=f2bf(a.y); o[2]=f2bf(a.z); o[3]=f2bf(a.w);
  o[4]=f2bf(c.x); o[5]=f2bf(c.y); o[6]=f2bf(c.z); o[7]=f2bf(c.w);
  *(ushortx8*)(dst + (size_t)i*8) = o;
}

// ---------------- weight transpose + cast: w (K,N) fp32 -> wt (N,K) bf16 ----------------
__global__ __launch_bounds__(256) void transpose_cvt(const float* __restrict__ w,
                                                     u16* __restrict__ wt, int K, int N) {
  __shared__ float tile[32][33];
  int n0 = blockIdx.x * 32, k0 = blockIdx.y * 32;
  int tx = threadIdx.x & 31, ty = threadIdx.x >> 5;
#pragma unroll
  for (int i = 0; i < 4; i++) {
    int r = ty*4 + i;
    tile[r][tx] = w[(size_t)(k0 + r)*N + n0 + tx];
  }
  __syncthreads();
#pragma unroll
  for (int i = 0; i < 4; i++) {
    int n = ty*4 + i;
    wt[(size_t)(n0 + n)*K + k0 + tx] = f2bf(tile[tx][n]);
  }
}

// ---------------- GEMM: C(M,N) = A(M,K) @ Bt(N,K)^T, bf16 in, fp32 acc ----------------
// m97 structure + XOR-swizzled LDS: 128x128 tile, BK=64, global_load_lds width-16.
template<int OUT_BF16>
__global__ __launch_bounds__(256) void gemm_bt(const u16* __restrict__ A,
                                               const u16* __restrict__ Bt,
                                               void* __restrict__ Cv,
                                               int M, int N, int K) {
  __shared__ u16 As[128*64];
  __shared__ u16 Bs[128*64];
  const int tid = threadIdx.x;
  const int w = tid >> 6, l = tid & 63, quad = l >> 4, c16 = l & 15;
  const int bm = blockIdx.y * 128, bn = blockIdx.x * 128;
  const int wm = (w & 1) * 64, wn = (w >> 1) * 64;
  const int drow = l >> 3;                  // 0..7  (8 rows per 1KB DMA instr)
  const int gchunk = (l & 7) ^ drow;        // swizzled global chunk this lane fetches
  const int dcol = gchunk * 8;              // u16 col offset
  floatx4 acc[4][4];
#pragma unroll
  for (int mi = 0; mi < 4; mi++)
#pragma unroll
    for (int ni = 0; ni < 4; ni++) acc[mi][ni] = floatx4{0.f,0.f,0.f,0.f};

  for (int k0 = 0; k0 < K; k0 += 64) {
    __syncthreads();
#pragma unroll
    for (int j = 0; j < 4; j++) {
      int row = w*32 + j*8 + drow;          // rowbase&7 == 0, so row&7 == drow
      __builtin_amdgcn_global_load_lds(
          (gbl_u32*)(A + (size_t)(bm + row)*K + k0 + dcol),
          (lds_u32*)(As + (w*32 + j*8)*64), 16, 0, 0);
      __builtin_amdgcn_global_load_lds(
          (gbl_u32*)(Bt + (size_t)(bn + row)*K + k0 + dcol),
          (lds_u32*)(Bs + (w*32 + j*8)*64), 16, 0, 0);
    }
    __syncthreads();
#pragma unroll
    for (int ks = 0; ks < 2; ks++) {
      shortx8 af[4], bfr[4];
#pragma unroll
      for (int mi = 0; mi < 4; mi++) {
        int row = wm + mi*16 + c16;
        int ch  = (ks*4 + quad) ^ (row & 7);
        af[mi] = ldfrag(As + row*64 + ch*8);
      }
#pragma unroll
      for (int ni = 0; ni < 4; ni++) {
        int row = wn + ni*16 + c16;
        int ch  = (ks*4 + quad) ^ (row & 7);
        bfr[ni] = ldfrag(Bs + row*64 + ch*8);
      }
#pragma unroll
      for (int mi = 0; mi < 4; mi++)
#pragma unroll
        for (int ni = 0; ni < 4; ni++)
          acc[mi][ni] = __builtin_amdgcn_mfma_f32_16x16x32_bf16(af[mi], bfr[ni], acc[mi][ni], 0, 0, 0);
    }
  }
  // epilogue: C/D layout col=lane&15, row=quad*4+reg
#pragma unroll
  for (int mi = 0; mi < 4; mi++)
#pragma unroll
    for (int i = 0; i < 4; i++) {
      int row = bm + wm + mi*16 + quad*4 + i;
#pragma unroll
      for (int ni = 0; ni < 4; ni++) {
        int col = bn + wn + ni*16 + c16;
        float v = acc[mi][ni][i];
        if (OUT_BF16) ((u16*)Cv)[(size_t)row*N + col] = f2bf(v);
        else          ((float*)Cv)[(size_t)row*N + col] = v;
      }
    }
}

// ---------------- RoPE on q,k parts of qkv_pre; Q pre-scaled by log2e/sqrt(HD) ----------------
__global__ __launch_bounds__(256) void rope_kernel(const u16* __restrict__ qkv,
                                                   const float* __restrict__ fc,
                                                   const float* __restrict__ fs,
                                                   u16* __restrict__ q_r,
                                                   u16* __restrict__ k_r) {
  u32 idx  = blockIdx.x * 256 + threadIdx.x;     // MTOT*40*64 pairs
  u32 t    = idx & 63;
  u32 rest = idx >> 6;
  u32 m    = rest / 40u;
  u32 hh   = rest - m*40u;
  u32 s    = m & (S_ - 1);
  float c  = fc[s*64 + t], sn = fs[s*64 + t];
  u32 src; u16* dst; u32 dstoff; float scale;
  if (hh < (u32)NH_) {
    src = m*NQKV + hh*HD_ + 2*t;  dst = q_r;  dstoff = m*(NH_*HD_) + hh*HD_ + 2*t;  scale = QSCALE;
  } else {
    u32 hk = hh - NH_;
    src = m*NQKV + NH_*HD_ + hk*HD_ + 2*t;  dst = k_r;  dstoff = m*(NKV_*HD_) + hk*HD_ + 2*t;  scale = KSCALE;
  }
  u32 pair = *(const u32*)(qkv + src);
  float xr = bf2f((u16)(pair & 0xffffu));
  float xi = bf2f((u16)(pair >> 16));
  float orr = (xr*c - xi*sn) * scale;
  float oii = (xr*sn + xi*c) * scale;
  u32 outp = (u32)f2bf(orr) | ((u32)f2bf(oii) << 16);
  *(u32*)(dst + dstoff) = outp;
}

// ---------------- V transpose: qkv_pre v-part (m, hk, d) -> vt (b, hk, d, s) ----------------
__global__ __launch_bounds__(256) void v_transpose(const u16* __restrict__ qkv,
                                                   u16* __restrict__ vt) {
  __shared__ u16 tile[32][33];
  int bh = blockIdx.y; int b = bh >> 3, hk = bh & 7;
  int ts = (blockIdx.x & 63) * 32;   // s tile
  int td = (blockIdx.x >> 6) * 32;   // d tile
  int tx = threadIdx.x & 31, ty = threadIdx.x >> 5;
#pragma unroll
  for (int i = 0; i < 4; i++) {
    int r = ty*4 + i;
    tile[r][tx] = qkv[(size_t)(b*S_ + ts + r)*NQKV + (NH_*HD_ + NKV_*HD_) + hk*HD_ + td + tx];
  }
  __syncthreads();
#pragma unroll
  for (int i = 0; i < 4; i++) {
    int d = ty*4 + i;
    vt[((size_t)bh*HD_ + td + d)*S_ + ts + tx] = tile[tx][d];
  }
}

// ---------------- Flash attention: 64-query tile per block, online softmax (log2 domain) ----------------
// Round-1 changes vs 964us baseline:
//  (a) K/V/Q staging via swizzled-source global_load_lds (same pattern as gemm_bt),
//      replacing per-thread VGPR round-trip staging into padded LDS.  LDS layout is
//      linear [rows][chunks] with logical chunk c of row r stored at slot c^(r&7):
//      2 lanes/bank on all ds_read_b128 fragment reads (free, m136).
//  (b) s_setprio(1) around both MFMA clusters (T5).
//  (c) defer-max online softmax (T13, THR=8 in log2 domain): skip max-update +
//      O-rescale when the wave-uniform vote says tile max grew < 8 bits.
__global__ __launch_bounds__(256) void attn_kernel(const u16* __restrict__ Q,
                                                   const u16* __restrict__ Kr,
                                                   const u16* __restrict__ Vt,
                                                   u16* __restrict__ Out) {
  __shared__ u16 Qs[64*128];         // swizzled Q tile; per-wave P overlay after aq load
  __shared__ u16 Ks[64*128];         // swizzled K tile (rows = key idx, 16 chunks)
  __shared__ u16 Vts[128*64];        // swizzled V^T tile (rows = d, 8 chunks)
  const int tid = threadIdx.x;
  const int w = tid >> 6, l = tid & 63, quad = l >> 4, c16 = l & 15;
  const int qt = blockIdx.x, h = blockIdx.y, b = blockIdx.z;
  const int hk = h >> 2;                 // GQA: 4 query heads per kv head

  // ---- stage Q tile (64 x 128) via DMA: wave w covers rows [w*16, w*16+16) ----
  {
    const u16* qbase = Q + (size_t)(b*S_ + qt*64)*(NH_*HD_) + h*HD_;
#pragma unroll
    for (int j = 0; j < 4; j++) {
      int rowb = w*16 + j*4;
      int r = rowb + (l >> 4);
      int gch = (l & 15) ^ (r & 7);
      __builtin_amdgcn_global_load_lds(
          (gbl_u32*)(qbase + (size_t)r*(NH_*HD_) + gch*8),
          (lds_u32*)(Qs + rowb*128), 16, 0, 0);
    }
  }
  __syncthreads();
  shortx8 aq[4];
#pragma unroll
  for (int kk = 0; kk < 4; kk++)
    aq[kk] = ldfrag(Qs + (w*16 + c16)*128 + ((kk*4 + quad) ^ (c16 & 7))*8);

  floatx4 o[8];
#pragma unroll
  for (int f = 0; f < 8; f++) o[f] = floatx4{0.f,0.f,0.f,0.f};
  float mrow[4] = {-1e30f,-1e30f,-1e30f,-1e30f};
  float lrow[4] = {0.f,0.f,0.f,0.f};
  u16* pw = Qs + (w*16)*128;     // P overlay on dead Qs region (per-wave private 16 rows)

  const u16* kbase = Kr + (size_t)(b*S_)*(NKV_*HD_) + hk*HD_;
  const u16* vbase = Vt + (size_t)(b*NKV_ + hk)*HD_*S_;

  for (int kt = 0; kt < S_/64; kt++) {
    __syncthreads();               // prev iter's fragment reads drained
    // DMA stage: K rows [w*16,w*16+16), V rows [w*32,w*32+32); 8 x 1KB instrs / wave
#pragma unroll
    for (int j = 0; j < 4; j++) {
      int rowb = w*16 + j*4;
      int r = rowb + (l >> 4);
      int gch = (l & 15) ^ (r & 7);
      __builtin_amdgcn_global_load_lds(
          (gbl_u32*)(kbase + (size_t)(kt*64 + r)*(NKV_*HD_) + gch*8),
          (lds_u32*)(Ks + rowb*128), 16, 0, 0);
      int rowbv = w*32 + j*8;
      int rv = rowbv + (l >> 3);
      int gchv = (l & 7) ^ (rv & 7);
      __builtin_amdgcn_global_load_lds(
          (gbl_u32*)(vbase + (size_t)rv*S_ + kt*64 + gchv*8),
          (lds_u32*)(Vts + rowbv*64), 16, 0, 0);
    }
    __syncthreads();               // vmcnt(0) drained by compiler before barrier

    // S = Q K^T  (log2-domain: Q pre-scaled by log2e/sqrt(HD))
    floatx4 sc[4];
#pragma unroll
    for (int nt = 0; nt < 4; nt++) sc[nt] = floatx4{0.f,0.f,0.f,0.f};
    __builtin_amdgcn_s_setprio(1);
#pragma unroll
    for (int kk = 0; kk < 4; kk++)
#pragma unroll
      for (int nt = 0; nt < 4; nt++) {
        int rowk = nt*16 + c16;
        shortx8 bk = ldfrag(Ks + rowk*128 + ((kk*4 + quad) ^ (c16 & 7))*8);
        sc[nt] = __builtin_amdgcn_mfma_f32_16x16x32_bf16(aq[kk], bk, sc[nt], 0, 0, 0);
      }
    __builtin_amdgcn_s_setprio(0);

    // online softmax: row r = quad*4+i, reduce across the 16 lanes of this quad
    float mx4[4];
    float need = -1e30f;
#pragma unroll
    for (int i = 0; i < 4; i++) {
      float mx = fmaxf(fmaxf(sc[0][i], sc[1][i]), fmaxf(sc[2][i], sc[3][i]));
      mx = fmaxf(mx, __shfl_xor(mx, 1));
      mx = fmaxf(mx, __shfl_xor(mx, 2));
      mx = fmaxf(mx, __shfl_xor(mx, 4));
      mx = fmaxf(mx, __shfl_xor(mx, 8));
      mx4[i] = mx;
      need = fmaxf(need, mx - mrow[i]);
    }
    if (__all(need <= 8.0f)) {
      // defer: keep old max, P bounded by 2^8, no O rescale
#pragma unroll
      for (int i = 0; i < 4; i++) {
        float rs = 0.f;
#pragma unroll
        for (int nt = 0; nt < 4; nt++) {
          float p = __builtin_amdgcn_exp2f(sc[nt][i] - mrow[i]);
          sc[nt][i] = p; rs += p;
        }
        rs += __shfl_xor(rs, 1);
        rs += __shfl_xor(rs, 2);
        rs += __shfl_xor(rs, 4);
        rs += __shfl_xor(rs, 8);
        lrow[i] += rs;
      }
    } else {
      float alpha[4];
#pragma unroll
      for (int i = 0; i < 4; i++) {
        float mn = fmaxf(mrow[i], mx4[i]);
        float al = __builtin_amdgcn_exp2f(mrow[i] - mn);
        mrow[i] = mn;
        float rs = 0.f;
#pragma unroll
        for (int nt = 0; nt < 4; nt++) {
          float p = __builtin_amdgcn_exp2f(sc[nt][i] - mn);
          sc[nt][i] = p; rs += p;
        }
        rs += __shfl_xor(rs, 1);
        rs += __shfl_xor(rs, 2);
        rs += __shfl_xor(rs, 4);
        rs += __shfl_xor(rs, 8);
        lrow[i] = lrow[i]*al + rs;
        alpha[i] = al;
      }
#pragma unroll
      for (int f = 0; f < 8; f++)
#pragma unroll
        for (int i = 0; i < 4; i++) o[f][i] *= alpha[i];
    }

    // P: C-layout regs -> swizzled LDS overlay -> A-layout frags (per-wave private)
#pragma unroll
    for (int nt = 0; nt < 4; nt++)
#pragma unroll
      for (int i = 0; i < 4; i++) {
        int pr = quad*4 + i;
        int ch = (nt*2 + (c16 >> 3)) ^ (pr & 7);
        pw[pr*128 + ch*8 + (c16 & 7)] = f2bf(sc[nt][i]);
      }
    asm volatile("s_waitcnt lgkmcnt(0)" ::: "memory");

    // O += P @ V
    __builtin_amdgcn_s_setprio(1);
#pragma unroll
    for (int kk2 = 0; kk2 < 2; kk2++) {
      shortx8 pf = ldfrag(pw + c16*128 + ((kk2*4 + quad) ^ (c16 & 7))*8);
#pragma unroll
      for (int f = 0; f < 8; f++) {
        int rv = f*16 + c16;
        shortx8 vf = ldfrag(Vts + rv*64 + ((kk2*4 + quad) ^ (rv & 7))*8);
        o[f] = __builtin_amdgcn_mfma_f32_16x16x32_bf16(pf, vf, o[f], 0, 0, 0);
      }
    }
    __builtin_amdgcn_s_setprio(0);
  }

  // normalize + store bf16
#pragma unroll
  for (int i = 0; i < 4; i++) {
    int srow = qt*64 + w*16 + quad*4 + i;
    float inv = 1.f / lrow[i];
    size_t base = (size_t)(b*S_ + srow)*(NH_*HD_) + h*HD_;
#pragma unroll
    for (int f = 0; f < 8; f++)
      Out[base + f*16 + c16] = f2bf(o[f][i] * inv);
  }
}

extern "C" void kernel_launch(void* const* d_in, const int* in_sizes, int n_in,
                              void* d_out, int out_size, void* d_ws, size_t ws_size,
                              hipStream_t stream) {
  (void)in_sizes; (void)n_in; (void)out_size; (void)ws_size;
  const float* x  = (const float*)d_in[0];
  // d_in[1] = start_pos (unused; reference ignores it)
  const float* fc = (const float*)d_in[2];
  const float* fs = (const float*)d_in[3];
  const float* wq = (const float*)d_in[4];
  const float* wk = (const float*)d_in[5];
  const float* wv = (const float*)d_in[6];
  const float* wo = (const float*)d_in[7];
  float* out = (float*)d_out;

  // workspace layout (160 MB total), with lifetime-based reuse:
  char* ws = (char*)d_ws;
  u16* xb    = (u16*)(ws);                    // x bf16 (33.5MB); reused as attn_out after QKV
  u16* wallt = (u16*)(ws + 33554432ull);      // [wq|wk|wv]^T bf16, 6144x4096 (50.3MB)
  u16* q_r   = (u16*)(ws + 33554432ull);      // overlays wallt after QKV GEMM (33.5MB)
  u16* k_r   = (u16*)(ws + 67108864ull);      // (8.4MB)
  u16* vt    = (u16*)(ws + 75497472ull);      // (8.4MB)
  u16* wot   = (u16*)(ws + 83886080ull);      // wo^T bf16 (33.5MB)
  u16* qkvp  = (u16*)(ws + 117440512ull);     // qkv_pre bf16, 4096x6144 (50.3MB); end 160MB

  cvt_f32_bf16<<<8192, 256, 0, stream>>>(x, xb);
  transpose_cvt<<<dim3(128,128), 256, 0, stream>>>(wq, wallt, 4096, 4096);
  transpose_cvt<<<dim3(32,128),  256, 0, stream>>>(wk, wallt + (size_t)4096*4096, 4096, 1024);
  transpose_cvt<<<dim3(32,128),  256, 0, stream>>>(wv, wallt + (size_t)5120*4096, 4096, 1024);
  transpose_cvt<<<dim3(128,128), 256, 0, stream>>>(wo, wot, 4096, 4096);

  gemm_bt<1><<<dim3(48,32), 256, 0, stream>>>(xb, wallt, qkvp, MTOT, NQKV, DIM_);

  rope_kernel<<<40960, 256, 0, stream>>>(qkvp, fc, fs, q_r, k_r);
  v_transpose<<<dim3(256,16), 256, 0, stream>>>(qkvp, vt);

  attn_kernel<<<dim3(32,32,2), 256, 0, stream>>>(q_r, k_r, vt, xb);

  gemm_bt<0><<<dim3(32,32), 256, 0, stream>>>(xb, wot, out, MTOT, DIM_, 4096);
}

// Round 2
// 908.703 us; speedup vs baseline: 1.0629x; 1.0629x over previous
//
#include <hip/hip_runtime.h>

typedef unsigned short u16;
typedef unsigned int   u32;
typedef __attribute__((ext_vector_type(4))) float floatx4;
typedef __attribute__((ext_vector_type(8))) short shortx8;
typedef __attribute__((ext_vector_type(8))) u16   ushortx8;

#define B_   2
#define S_   2048
#define DIM_ 4096
#define NH_  32
#define NKV_ 8
#define HD_  128
#define MTOT (B_*S_)            // 4096 rows
#define NQKV (NH_*HD_ + 2*NKV_*HD_)  // 6144
// Q pre-scale: 1/sqrt(128) * log2(e)  -> scores in log2 domain, softmax uses exp2
#define QSCALE 0.12753785735803168f
#define KSCALE 1.0f

typedef __attribute__((address_space(3))) u32 lds_u32;
typedef const __attribute__((address_space(1))) u32 gbl_u32;

__device__ inline u16 f2bf(float f) {                 // native RNE cvt
  __bf16 h = (__bf16)f;
  return __builtin_bit_cast(u16, h);
}
__device__ inline float bf2f(u16 u) {
  u32 x = ((u32)u) << 16;
  return __builtin_bit_cast(float, x);
}
__device__ inline shortx8 ldfrag(const u16* p) {
  return __builtin_bit_cast(shortx8, *(const uint4*)p);
}

// ---------------- fp32 -> bf16 cast (x) ----------------
__global__ __launch_bounds__(256) void cvt_f32_bf16(const float* __restrict__ src,
                                                    u16* __restrict__ dst) {
  int i = blockIdx.x * 256 + threadIdx.x;          // 8 elems / thread
  const float4* s4 = (const float4*)src;
  float4 a = s4[2*i], c = s4[2*i+1];
  ushortx8 o;
  o[0]=f2bf(a.x); o[1]=f2bf(a.y); o[2]=f2bf(a.z); o[3]=f2bf(a.w);
  o[4]=f2bf(c.x); o[5]=f2bf(c.y); o[6]=f2bf(c.z); o[7]=f2bf(c.w);
  *(ushortx8*)(dst + (size_t)i*8) = o;
}

// ---------------- weight transpose + cast: w (K,N) fp32 -> wt (N,K) bf16 ----------------
__global__ __launch_bounds__(256) void transpose_cvt(const float* __restrict__ w,
                                                     u16* __restrict__ wt, int K, int N) {
  __shared__ float tile[32][33];
  int n0 = blockIdx.x * 32, k0 = blockIdx.y * 32;
  int tx = threadIdx.x & 31, ty = threadIdx.x >> 5;
#pragma unroll
  for (int i = 0; i < 4; i++) {
    int r = ty*4 + i;
    tile[r][tx] = w[(size_t)(k0 + r)*N + n0 + tx];
  }
  __syncthreads();
#pragma unroll
  for (int i = 0; i < 4; i++) {
    int n = ty*4 + i;
    wt[(size_t)(n0 + n)*K + k0 + tx] = f2bf(tile[tx][n]);
  }
}

// ---------------- GEMM: C(M,N) = A(M,K) @ Bt(N,K)^T, bf16 in, fp32 acc ----------------
// m97 structure + XOR-swizzled LDS: 128x128 tile, BK=64, global_load_lds width-16.
template<int OUT_BF16>
__global__ __launch_bounds__(256) void gemm_bt(const u16* __restrict__ A,
                                               const u16* __restrict__ Bt,
                                               void* __restrict__ Cv,
                                               int M, int N, int K) {
  __shared__ u16 As[128*64];
  __shared__ u16 Bs[128*64];
  const int tid = threadIdx.x;
  const int w = tid >> 6, l = tid & 63, quad = l >> 4, c16 = l & 15;
  const int bm = blockIdx.y * 128, bn = blockIdx.x * 128;
  const int wm = (w & 1) * 64, wn = (w >> 1) * 64;
  const int drow = l >> 3;                  // 0..7  (8 rows per 1KB DMA instr)
  const int gchunk = (l & 7) ^ drow;        // swizzled global chunk this lane fetches
  const int dcol = gchunk * 8;              // u16 col offset
  floatx4 acc[4][4];
#pragma unroll
  for (int mi = 0; mi < 4; mi++)
#pragma unroll
    for (int ni = 0; ni < 4; ni++) acc[mi][ni] = floatx4{0.f,0.f,0.f,0.f};

  for (int k0 = 0; k0 < K; k0 += 64) {
    __syncthreads();
#pragma unroll
    for (int j = 0; j < 4; j++) {
      int row = w*32 + j*8 + drow;          // rowbase&7 == 0, so row&7 == drow
      __builtin_amdgcn_global_load_lds(
          (gbl_u32*)(A + (size_t)(bm + row)*K + k0 + dcol),
          (lds_u32*)(As + (w*32 + j*8)*64), 16, 0, 0);
      __builtin_amdgcn_global_load_lds(
          (gbl_u32*)(Bt + (size_t)(bn + row)*K + k0 + dcol),
          (lds_u32*)(Bs + (w*32 + j*8)*64), 16, 0, 0);
    }
    __syncthreads();
#pragma unroll
    for (int ks = 0; ks < 2; ks++) {
      shortx8 af[4], bfr[4];
#pragma unroll
      for (int mi = 0; mi < 4; mi++) {
        int row = wm + mi*16 + c16;
        int ch  = (ks*4 + quad) ^ (row & 7);
        af[mi] = ldfrag(As + row*64 + ch*8);
      }
#pragma unroll
      for (int ni = 0; ni < 4; ni++) {
        int row = wn + ni*16 + c16;
        int ch  = (ks*4 + quad) ^ (row & 7);
        bfr[ni] = ldfrag(Bs + row*64 + ch*8);
      }
#pragma unroll
      for (int mi = 0; mi < 4; mi++)
#pragma unroll
        for (int ni = 0; ni < 4; ni++)
          acc[mi][ni] = __builtin_amdgcn_mfma_f32_16x16x32_bf16(af[mi], bfr[ni], acc[mi][ni], 0, 0, 0);
    }
  }
  // epilogue: C/D layout col=lane&15, row=quad*4+reg
#pragma unroll
  for (int mi = 0; mi < 4; mi++)
#pragma unroll
    for (int i = 0; i < 4; i++) {
      int row = bm + wm + mi*16 + quad*4 + i;
#pragma unroll
      for (int ni = 0; ni < 4; ni++) {
        int col = bn + wn + ni*16 + c16;
        float v = acc[mi][ni][i];
        if (OUT_BF16) ((u16*)Cv)[(size_t)row*N + col] = f2bf(v);
        else          ((float*)Cv)[(size_t)row*N + col] = v;
      }
    }
}

// ---------------- RoPE on q,k parts of qkv_pre; Q pre-scaled by log2e/sqrt(HD) ----------------
__global__ __launch_bounds__(256) void rope_kernel(const u16* __restrict__ qkv,
                                                   const float* __restrict__ fc,
                                                   const float* __restrict__ fs,
                                                   u16* __restrict__ q_r,
                                                   u16* __restrict__ k_r) {
  u32 idx  = blockIdx.x * 256 + threadIdx.x;     // MTOT*40*64 pairs
  u32 t    = idx & 63;
  u32 rest = idx >> 6;
  u32 m    = rest / 40u;
  u32 hh   = rest - m*40u;
  u32 s    = m & (S_ - 1);
  float c  = fc[s*64 + t], sn = fs[s*64 + t];
  u32 src; u16* dst; u32 dstoff; float scale;
  if (hh < (u32)NH_) {
    src = m*NQKV + hh*HD_ + 2*t;  dst = q_r;  dstoff = m*(NH_*HD_) + hh*HD_ + 2*t;  scale = QSCALE;
  } else {
    u32 hk = hh - NH_;
    src = m*NQKV + NH_*HD_ + hk*HD_ + 2*t;  dst = k_r;  dstoff = m*(NKV_*HD_) + hk*HD_ + 2*t;  scale = KSCALE;
  }
  u32 pair = *(const u32*)(qkv + src);
  float xr = bf2f((u16)(pair & 0xffffu));
  float xi = bf2f((u16)(pair >> 16));
  float orr = (xr*c - xi*sn) * scale;
  float oii = (xr*sn + xi*c) * scale;
  u32 outp = (u32)f2bf(orr) | ((u32)f2bf(oii) << 16);
  *(u32*)(dst + dstoff) = outp;
}

// ---------------- V transpose: qkv_pre v-part (m, hk, d) -> vt (b, hk, d, s) ----------------
__global__ __launch_bounds__(256) void v_transpose(const u16* __restrict__ qkv,
                                                   u16* __restrict__ vt) {
  __shared__ u16 tile[32][33];
  int bh = blockIdx.y; int b = bh >> 3, hk = bh & 7;
  int ts = (blockIdx.x & 63) * 32;   // s tile
  int td = (blockIdx.x >> 6) * 32;   // d tile
  int tx = threadIdx.x & 31, ty = threadIdx.x >> 5;
#pragma unroll
  for (int i = 0; i < 4; i++) {
    int r = ty*4 + i;
    tile[r][tx] = qkv[(size_t)(b*S_ + ts + r)*NQKV + (NH_*HD_ + NKV_*HD_) + hk*HD_ + td + tx];
  }
  __syncthreads();
#pragma unroll
  for (int i = 0; i < 4; i++) {
    int d = ty*4 + i;
    vt[((size_t)bh*HD_ + td + d)*S_ + ts + tx] = tile[tx][d];
  }
}

// ---------------- Flash attention: 64-query tile per block, online softmax (log2 domain) ----------------
// Round-2 changes (counters showed latency-bound: Mfma 16%, VALU 38%, HBM 4%, occ 22%):
//  (a) K/V double-buffer 2-phase pipeline: issue tile t+1's DMA right after the
//      barrier, compute tile t, next barrier's implicit vmcnt(0) drains loads that
//      had a full compute phase to land.  Removes exposed load latency from the
//      per-tile serial chain.  LDS 48->80KB (2 blocks/CU).
//  (b) Row-sum via ones-column MFMA (lacc = mfma(pf, ones, lacc)) -- deletes the
//      4x 4-deep __shfl_xor sum-reduce chain and all lrow bookkeeping; slow-path
//      alpha applies to lacc exactly like o.
//  (c) Fast-path max check: lane-local fmax tree + ONE 4-deep shuffle chain,
//      compared against min(mrow)+8 (conservative).  Slow path keeps exact per-row.
__global__ __launch_bounds__(256) void attn_kernel(const u16* __restrict__ Q,
                                                   const u16* __restrict__ Kr,
                                                   const u16* __restrict__ Vt,
                                                   u16* __restrict__ Out) {
  __shared__ u16 Qs[64*128];         // swizzled Q tile; per-wave P overlay after aq load
  __shared__ u16 Ks[2][64*128];      // swizzled K tiles, double-buffered
  __shared__ u16 Vts[2][128*64];     // swizzled V^T tiles, double-buffered
  const int tid = threadIdx.x;
  const int w = tid >> 6, l = tid & 63, quad = l >> 4, c16 = l & 15;
  const int qt = blockIdx.x, h = blockIdx.y, b = blockIdx.z;
  const int hk = h >> 2;                 // GQA: 4 query heads per kv head

  const u16* kbase = Kr + (size_t)(b*S_)*(NKV_*HD_) + hk*HD_;
  const u16* vbase = Vt + (size_t)(b*NKV_ + hk)*HD_*S_;

  // ---- stage Q tile (64 x 128) via DMA: wave w covers rows [w*16, w*16+16) ----
  {
    const u16* qbase = Q + (size_t)(b*S_ + qt*64)*(NH_*HD_) + h*HD_;
#pragma unroll
    for (int j = 0; j < 4; j++) {
      int rowb = w*16 + j*4;
      int r = rowb + (l >> 4);
      int gch = (l & 15) ^ (r & 7);
      __builtin_amdgcn_global_load_lds(
          (gbl_u32*)(qbase + (size_t)r*(NH_*HD_) + gch*8),
          (lds_u32*)(Qs + rowb*128), 16, 0, 0);
    }
  }
  // ---- stage K/V tile 0 into buffer 0 ----
#pragma unroll
  for (int j = 0; j < 4; j++) {
    int rowb = w*16 + j*4;
    int r = rowb + (l >> 4);
    int gch = (l & 15) ^ (r & 7);
    __builtin_amdgcn_global_load_lds(
        (gbl_u32*)(kbase + (size_t)r*(NKV_*HD_) + gch*8),
        (lds_u32*)(Ks[0] + rowb*128), 16, 0, 0);
    int rowbv = w*32 + j*8;
    int rv = rowbv + (l >> 3);
    int gchv = (l & 7) ^ (rv & 7);
    __builtin_amdgcn_global_load_lds(
        (gbl_u32*)(vbase + (size_t)rv*S_ + gchv*8),
        (lds_u32*)(Vts[0] + rowbv*64), 16, 0, 0);
  }
  __syncthreads();                     // drains Q + tile-0 DMA

  shortx8 aq[4];
#pragma unroll
  for (int kk = 0; kk < 4; kk++)
    aq[kk] = ldfrag(Qs + (w*16 + c16)*128 + ((kk*4 + quad) ^ (c16 & 7))*8);

  shortx8 vones;
#pragma unroll
  for (int e = 0; e < 8; e++) vones[e] = (short)0x3F80;   // bf16 1.0

  floatx4 o[8];
#pragma unroll
  for (int f = 0; f < 8; f++) o[f] = floatx4{0.f,0.f,0.f,0.f};
  floatx4 lacc = floatx4{0.f,0.f,0.f,0.f};   // row-sum accumulator (ones-column of V)
  float mrow[4] = {-1e30f,-1e30f,-1e30f,-1e30f};
  u16* pw = Qs + (w*16)*128;     // P overlay on dead Qs region (per-wave private 16 rows)

  int cur = 0;
  for (int kt = 0; kt < S_/64; kt++) {
    if (kt) __syncthreads();     // drains buf[cur] DMA (vmcnt 0) + prev reads of buf[cur^1]

    // prefetch tile kt+1 into buf[cur^1]; latency hides under this tile's compute
    if (kt + 1 < S_/64) {
      int nb = cur ^ 1;
#pragma unroll
      for (int j = 0; j < 4; j++) {
        int rowb = w*16 + j*4;
        int r = rowb + (l >> 4);
        int gch = (l & 15) ^ (r & 7);
        __builtin_amdgcn_global_load_lds(
            (gbl_u32*)(kbase + (size_t)((kt+1)*64 + r)*(NKV_*HD_) + gch*8),
            (lds_u32*)(Ks[nb] + rowb*128), 16, 0, 0);
        int rowbv = w*32 + j*8;
        int rv = rowbv + (l >> 3);
        int gchv = (l & 7) ^ (rv & 7);
        __builtin_amdgcn_global_load_lds(
            (gbl_u32*)(vbase + (size_t)rv*S_ + (kt+1)*64 + gchv*8),
            (lds_u32*)(Vts[nb] + rowbv*64), 16, 0, 0);
      }
    }

    // S = Q K^T  (log2-domain: Q pre-scaled by log2e/sqrt(HD))
    floatx4 sc[4];
#pragma unroll
    for (int nt = 0; nt < 4; nt++) sc[nt] = floatx4{0.f,0.f,0.f,0.f};
    __builtin_amdgcn_s_setprio(1);
#pragma unroll
    for (int kk = 0; kk < 4; kk++)
#pragma unroll
      for (int nt = 0; nt < 4; nt++) {
        int rowk = nt*16 + c16;
        shortx8 bk = ldfrag(Ks[cur] + rowk*128 + ((kk*4 + quad) ^ (c16 & 7))*8);
        sc[nt] = __builtin_amdgcn_mfma_f32_16x16x32_bf16(aq[kk], bk, sc[nt], 0, 0, 0);
      }
    __builtin_amdgcn_s_setprio(0);

    // fast-path check: combined max over this quad's 4 rows, one shuffle chain
    float mxall = fmaxf(fmaxf(fmaxf(sc[0][0], sc[0][1]), fmaxf(sc[0][2], sc[0][3])),
                        fmaxf(fmaxf(sc[1][0], sc[1][1]), fmaxf(sc[1][2], sc[1][3])));
    mxall = fmaxf(mxall,
                  fmaxf(fmaxf(fmaxf(sc[2][0], sc[2][1]), fmaxf(sc[2][2], sc[2][3])),
                        fmaxf(fmaxf(sc[3][0], sc[3][1]), fmaxf(sc[3][2], sc[3][3]))));
    mxall = fmaxf(mxall, __shfl_xor(mxall, 1));
    mxall = fmaxf(mxall, __shfl_xor(mxall, 2));
    mxall = fmaxf(mxall, __shfl_xor(mxall, 4));
    mxall = fmaxf(mxall, __shfl_xor(mxall, 8));
    float mlow = fminf(fminf(mrow[0], mrow[1]), fminf(mrow[2], mrow[3]));

    if (__all(mxall - mlow <= 8.0f)) {
      // defer: keep old maxes, P bounded by 2^8, no rescale, no sum-reduce (MFMA does it)
#pragma unroll
      for (int i = 0; i < 4; i++)
#pragma unroll
        for (int nt = 0; nt < 4; nt++)
          sc[nt][i] = __builtin_amdgcn_exp2f(sc[nt][i] - mrow[i]);
    } else {
      float alpha[4];
#pragma unroll
      for (int i = 0; i < 4; i++) {
        float mx = fmaxf(fmaxf(sc[0][i], sc[1][i]), fmaxf(sc[2][i], sc[3][i]));
        mx = fmaxf(mx, __shfl_xor(mx, 1));
        mx = fmaxf(mx, __shfl_xor(mx, 2));
        mx = fmaxf(mx, __shfl_xor(mx, 4));
        mx = fmaxf(mx, __shfl_xor(mx, 8));
        float mn = fmaxf(mrow[i], mx);
        alpha[i] = __builtin_amdgcn_exp2f(mrow[i] - mn);
        mrow[i] = mn;
#pragma unroll
        for (int nt = 0; nt < 4; nt++)
          sc[nt][i] = __builtin_amdgcn_exp2f(sc[nt][i] - mn);
      }
#pragma unroll
      for (int f = 0; f < 8; f++)
#pragma unroll
        for (int i = 0; i < 4; i++) o[f][i] *= alpha[i];
#pragma unroll
      for (int i = 0; i < 4; i++) lacc[i] *= alpha[i];
    }

    // P: C-layout regs -> swizzled LDS overlay -> A-layout frags (per-wave private)
#pragma unroll
    for (int nt = 0; nt < 4; nt++)
#pragma unroll
      for (int i = 0; i < 4; i++) {
        int pr = quad*4 + i;
        int ch = (nt*2 + (c16 >> 3)) ^ (pr & 7);
        pw[pr*128 + ch*8 + (c16 & 7)] = f2bf(sc[nt][i]);
      }
    asm volatile("s_waitcnt lgkmcnt(0)" ::: "memory");

    // O += P @ V; lacc accumulates P @ ones (row sums) via one extra MFMA per kk2
    __builtin_amdgcn_s_setprio(1);
#pragma unroll
    for (int kk2 = 0; kk2 < 2; kk2++) {
      shortx8 pf = ldfrag(pw + c16*128 + ((kk2*4 + quad) ^ (c16 & 7))*8);
      lacc = __builtin_amdgcn_mfma_f32_16x16x32_bf16(pf, vones, lacc, 0, 0, 0);
#pragma unroll
      for (int f = 0; f < 8; f++) {
        int rv = f*16 + c16;
        shortx8 vf = ldfrag(Vts[cur] + rv*64 + ((kk2*4 + quad) ^ (rv & 7))*8);
        o[f] = __builtin_amdgcn_mfma_f32_16x16x32_bf16(pf, vf, o[f], 0, 0, 0);
      }
    }
    __builtin_amdgcn_s_setprio(0);
    cur ^= 1;
  }

  // normalize + store bf16
#pragma unroll
  for (int i = 0; i < 4; i++) {
    int srow = qt*64 + w*16 + quad*4 + i;
    float inv = 1.f / lacc[i];
    size_t base = (size_t)(b*S_ + srow)*(NH_*HD_) + h*HD_;
#pragma unroll
    for (int f = 0; f < 8; f++)
      Out[base + f*16 + c16] = f2bf(o[f][i] * inv);
  }
}

extern "C" void kernel_launch(void* const* d_in, const int* in_sizes, int n_in,
                              void* d_out, int out_size, void* d_ws, size_t ws_size,
                              hipStream_t stream) {
  (void)in_sizes; (void)n_in; (void)out_size; (void)ws_size;
  const float* x  = (const float*)d_in[0];
  // d_in[1] = start_pos (unused; reference ignores it)
  const float* fc = (const float*)d_in[2];
  const float* fs = (const float*)d_in[3];
  const float* wq = (const float*)d_in[4];
  const float* wk = (const float*)d_in[5];
  const float* wv = (const float*)d_in[6];
  const float* wo = (const float*)d_in[7];
  float* out = (float*)d_out;

  // workspace layout (160 MB total), with lifetime-based reuse:
  char* ws = (char*)d_ws;
  u16* xb    = (u16*)(ws);                    // x bf16 (33.5MB); reused as attn_out after QKV
  u16* wallt = (u16*)(ws + 33554432ull);      // [wq|wk|wv]^T bf16, 6144x4096 (50.3MB)
  u16* q_r   = (u16*)(ws + 33554432ull);      // overlays wallt after QKV GEMM (33.5MB)
  u16* k_r   = (u16*)(ws + 67108864ull);      // (8.4MB)
  u16* vt    = (u16*)(ws + 75497472ull);      // (8.4MB)
  u16* wot   = (u16*)(ws + 83886080ull);      // wo^T bf16 (33.5MB)
  u16* qkvp  = (u16*)(ws + 117440512ull);     // qkv_pre bf16, 4096x6144 (50.3MB); end 160MB

  cvt_f32_bf16<<<8192, 256, 0, stream>>>(x, xb);
  transpose_cvt<<<dim3(128,128), 256, 0, stream>>>(wq, wallt, 4096, 4096);
  transpose_cvt<<<dim3(32,128),  256, 0, stream>>>(wk, wallt + (size_t)4096*4096, 4096, 1024);
  transpose_cvt<<<dim3(32,128),  256, 0, stream>>>(wv, wallt + (size_t)5120*4096, 4096, 1024);
  transpose_cvt<<<dim3(128,128), 256, 0, stream>>>(wo, wot, 4096, 4096);

  gemm_bt<1><<<dim3(48,32), 256, 0, stream>>>(xb, wallt, qkvp, MTOT, NQKV, DIM_);

  rope_kernel<<<40960, 256, 0, stream>>>(qkvp, fc, fs, q_r, k_r);
  v_transpose<<<dim3(256,16), 256, 0, stream>>>(qkvp, vt);

  attn_kernel<<<dim3(32,32,2), 256, 0, stream>>>(q_r, k_r, vt, xb);

  gemm_bt<0><<<dim3(32,32), 256, 0, stream>>>(xb, wot, out, MTOT, DIM_, 4096);
}